// Round 20
// baseline (427.387 us; speedup 1.0000x reference)
//
#include <hip/hip_runtime.h>
#include <hip/hip_bf16.h>

#define N_NODES 4096
#define N_EDGES 131072
#define N_GRAPHS 16
#define F_IN 128
#define D 128
#define QKVLD 1536   // 4 modules * 384
#define KSPL 2

typedef __hip_bfloat16 bf16;
typedef __attribute__((ext_vector_type(4))) float f32x4;
typedef __attribute__((ext_vector_type(8))) short bf16x8;

// float -> bf16 bits (RNE)
__device__ __forceinline__ short f2bf(float f) {
    unsigned u = __float_as_uint(f);
    unsigned r = (u + 0x7fffu + ((u >> 16) & 1u)) >> 16;
    return (short)r;
}
__device__ __forceinline__ float bf2f(short b) {
    return __uint_as_float(((unsigned)(unsigned short)b) << 16);
}
// Flagged load: isbf!=0 -> buffer holds bf16, else fp32. i is an ELEMENT index.
__device__ __forceinline__ float ldf(const void* p, long i, int isbf) {
    return isbf ? bf2f(((const short*)p)[i]) : ((const float*)p)[i];
}

// ---------------- dtype detector (bf16 data: all halfword exponents < 134) ----------------
__global__ void k_detect(const void* __restrict__ x, int* __restrict__ flag) {
    if (threadIdx.x == 0 && blockIdx.x == 0) {
        const unsigned short* h = (const unsigned short*)x;
        int bf = 1;
        for (int i = 0; i < 64; ++i) {
            int e = (h[i] >> 7) & 0xFF;
            if (e >= 134) { bf = 0; break; }
        }
        *flag = bf;
    }
}

// ---------------- flag-aware conversion of MFMA operand tensors to bf16 ----------------
struct ConvSegs {
    const void* src0; const void* src1; const void* src2; const void* src3; const void* src4;
    short* dst0; short* dst1; short* dst2; short* dst3; short* dst4;
    int e0, e1, e2, e3, e4;
};
__global__ void k_tobf16(ConvSegs s, const int* __restrict__ flag) {
    int idx = blockIdx.x * 256 + threadIdx.x;
    int isbf = *flag;
    const void* src; short* dst; int base;
    if (idx < s.e0)      { src = s.src0; dst = s.dst0; base = 0; }
    else if (idx < s.e1) { src = s.src1; dst = s.dst1; base = s.e0; }
    else if (idx < s.e2) { src = s.src2; dst = s.dst2; base = s.e1; }
    else if (idx < s.e3) { src = s.src3; dst = s.dst3; base = s.e2; }
    else if (idx < s.e4) { src = s.src4; dst = s.dst4; base = s.e3; }
    else return;
    int i = idx - base;
    dst[i] = f2bf(ldf(src, i, isbf));
}

__global__ void k_deg(const int* __restrict__ dst, int* __restrict__ degi) {
    int e = blockIdx.x * 256 + threadIdx.x;
    if (e < N_EDGES) atomicAdd(&degi[dst[e]], 1);
}

// ---------------- fused prep: degree scan + dinv + batch boundaries (one block) ----------------
__global__ __launch_bounds__(1024) void k_prep(const int* __restrict__ degi,
                                               const int* __restrict__ batch,
                                               int* __restrict__ offs,
                                               int* __restrict__ cursor,
                                               float* __restrict__ dinv,
                                               int* __restrict__ starts) {
    __shared__ int part[1024];
    int t = threadIdx.x;
    int4 v = *(const int4*)(degi + t * 4);
    int dv[4] = {v.x, v.y, v.z, v.w};
    int s = dv[0] + dv[1] + dv[2] + dv[3];
    part[t] = s;
    __syncthreads();
    for (int ofs = 1; ofs < 1024; ofs <<= 1) {
        int val = (t >= ofs) ? part[t - ofs] : 0;
        __syncthreads();
        part[t] += val;
        __syncthreads();
    }
    int o = part[t] - s;
#pragma unroll
    for (int j = 0; j < 4; ++j) {
        int n = t * 4 + j;
        offs[n] = o; cursor[n] = o;
        o += dv[j];
        dinv[n] = rsqrtf((float)(dv[j] + 1));   // +1 self loop
    }
    if (t == 1023) offs[4096] = o;
    // batch boundaries (batch is sorted)
#pragma unroll
    for (int j = 0; j < 4; ++j) {
        int n = t * 4 + j;
        int b = batch[n];
        if (n == 0) { for (int g2 = 0; g2 <= b; ++g2) starts[g2] = 0; }
        else {
            int pb = batch[n - 1];
            for (int g2 = pb + 1; g2 <= b; ++g2) starts[g2] = n;
        }
        if (n == N_NODES - 1) { for (int g2 = b + 1; g2 <= N_GRAPHS; ++g2) starts[g2] = N_NODES; }
    }
}

__global__ void k_sortedges(const int* __restrict__ src, const int* __restrict__ dst,
                            int* __restrict__ cursor, int* __restrict__ sSrc) {
    int e = blockIdx.x * 256 + threadIdx.x;
    if (e >= N_EDGES) return;
    int d = dst[e];
    int pos = atomicAdd(&cursor[d], 1);
    sSrc[pos] = src[e];
}

// ---------------- MFMA GEMM, bf16 out (no bias): C[M][ldc] bf16 = A @ W^T ----------------
__global__ __launch_bounds__(64) void k_mfma_gemm_s(const short* __restrict__ A, int lda,
                                                    const short* __restrict__ W,
                                                    short* __restrict__ C, int ldc, int K) {
    const int lane = threadIdx.x;
    const int m15 = lane & 15, quad = lane >> 4;
    const int c0 = blockIdx.x * 16;
    const int n0 = blockIdx.y * 16;
    f32x4 acc = {0.f, 0.f, 0.f, 0.f};
    for (int k0 = 0; k0 < K; k0 += 32) {
        bf16x8 a = *(const bf16x8*)(A + (long)(n0 + m15) * lda + k0 + quad * 8);
        bf16x8 b = *(const bf16x8*)(W + (long)(c0 + m15) * K + k0 + quad * 8);
        acc = __builtin_amdgcn_mfma_f32_16x16x32_bf16(a, b, acc, 0, 0, 0);
    }
#pragma unroll
    for (int i = 0; i < 4; ++i)
        C[(long)(n0 + quad * 4 + i) * ldc + c0 + m15] = f2bf(acc[i]);
}

// ---------------- fused qkv MFMA with scatter epilogue -> Qb/Kb/VTb bf16 ----------------
// Q pre-scaled by log2(e)/sqrt(32). V stored with per-32-tile slot permutation
// phys = 2*(off&15) + (off>=16) matching packed-P column order.
__global__ __launch_bounds__(64) void k_qkv(const short* __restrict__ h2b,
                                            const short* __restrict__ Winb,
                                            const void* __restrict__ bin,
                                            const int* __restrict__ flag,
                                            short* __restrict__ Qb,
                                            short* __restrict__ Kb,
                                            short* __restrict__ VTb) {
    const int lane = threadIdx.x;
    const int m15 = lane & 15, quad = lane >> 4;
    const int c0 = blockIdx.x * 16;
    const int n0 = blockIdx.y * 16;
    f32x4 acc = {0.f, 0.f, 0.f, 0.f};
#pragma unroll
    for (int k0 = 0; k0 < 128; k0 += 32) {
        bf16x8 a = *(const bf16x8*)(h2b + (long)(n0 + m15) * 128 + k0 + quad * 8);
        bf16x8 b = *(const bf16x8*)(Winb + (long)(c0 + m15) * 128 + k0 + quad * 8);
        acc = __builtin_amdgcn_mfma_f32_16x16x32_bf16(a, b, acc, 0, 0, 0);
    }
    const int c = c0 + m15;           // D layout: col = lane&15
    const int mmod = c / 384;
    const int r = c - mmod * 384;
    const int sect = r >> 7;          // 0=q, 1=k, 2=v (uniform per block)
    const int rr = r & 127;
    const int head = mmod * 4 + (rr >> 5);
    const int d = rr & 31;
    const float bias = ldf(bin, c, *flag);
    if (sect == 0) {
        const float scale = 0.17677669529663687f * 1.4426950408889634f;  // 1/sqrt(32)*log2(e)
#pragma unroll
        for (int i = 0; i < 4; ++i)   // D layout: row = quad*4 + i
            Qb[(long)head * 131072 + (long)(n0 + quad * 4 + i) * 32 + d] = f2bf((acc[i] + bias) * scale);
    } else if (sect == 1) {
#pragma unroll
        for (int i = 0; i < 4; ++i)
            Kb[(long)head * 131072 + (long)(n0 + quad * 4 + i) * 32 + d] = f2bf(acc[i] + bias);
    } else {
        long vbase = (long)head * 131072 + (long)d * 4096;
#pragma unroll
        for (int i = 0; i < 4; ++i) {
            int n = n0 + quad * 4 + i;
            int phys = (n & ~31) | (((n & 15) << 1) | ((n >> 4) & 1));
            VTb[vbase + phys] = f2bf(acc[i] + bias);
        }
    }
}

// ---------------- GCN gather (CSR, no atomics, bf16 lin input): one block per node ----------------
__global__ __launch_bounds__(64) void k_gather64(const short* __restrict__ hlin,
                                                 const int* __restrict__ offs,
                                                 const int* __restrict__ sSrc,
                                                 const float* __restrict__ dinv,
                                                 const void* __restrict__ bias,
                                                 const int* __restrict__ flag,
                                                 short* __restrict__ houtb) {
    int n = blockIdx.x;
    int c = threadIdx.x;
    int beg = offs[n], end = offs[n + 1];
    float di = dinv[n];
    float acc = 0.f;
    for (int j = beg; j < end; ++j) {
        int s = sSrc[j];
        acc += dinv[s] * bf2f(hlin[(long)s * 64 + c]);
    }
    float v = fmaxf(di * acc + di * di * bf2f(hlin[(long)n * 64 + c]) + ldf(bias, c, *flag), 0.f);
    houtb[(long)n * 64 + c] = f2bf(v);
}

__global__ __launch_bounds__(128) void k_gather128(const short* __restrict__ hlin,
                                                   const int* __restrict__ offs,
                                                   const int* __restrict__ sSrc,
                                                   const float* __restrict__ dinv,
                                                   const void* __restrict__ bias,
                                                   const int* __restrict__ flag,
                                                   short* __restrict__ h2b) {
    int n = blockIdx.x;
    int c = threadIdx.x;
    int beg = offs[n], end = offs[n + 1];
    float di = dinv[n];
    float acc = 0.f;
    for (int j = beg; j < end; ++j) {
        int s = sSrc[j];
        acc += dinv[s] * bf2f(hlin[(long)s * 128 + c]);
    }
    float v = fmaxf(di * acc + di * di * bf2f(hlin[(long)n * 128 + c]) + ldf(bias, c, *flag), 0.f);
    h2b[(long)n * 128 + c] = f2bf(v);
}

// ---------------- MFMA flash attention v7: XCD head-pinned, exp2, packed P, bf16 partials ----------------
__global__ __launch_bounds__(64) void k_attn_v7(const short* __restrict__ Qb,
                                                const short* __restrict__ Kb,
                                                const short* __restrict__ VTb,
                                                short* __restrict__ po_base,
                                                float* __restrict__ pl,
                                                int ksize) {
    const int lane = threadIdx.x;
    const int m15 = lane & 15, quad = lane >> 4;
    const int b = blockIdx.x;
    const int mh = (b & 7) + 8 * (b >> 11);     // head, pinned to b%8 (XCD round-robin)
    const int rem = (b >> 3) & 255;
    const int z = rem >> 7;                     // K-split
    const int q0 = (rem & 127) * 32;            // q tile
    const long hoff = (long)mh * 131072;
    const short* Qh = Qb + hoff;
    const short* Kh = Kb + hoff;
    const short* Vh = VTb + hoff;     // [32][4096], slot-permuted
    const int ks0 = z * ksize;
    const int kend = ks0 + ksize;

    const bf16x8 qf0 = *(const bf16x8*)(Qh + (long)(q0 + m15) * 32 + quad * 8);
    const bf16x8 qf1 = *(const bf16x8*)(Qh + (long)(q0 + 16 + m15) * 32 + quad * 8);

    f32x4 o00 = {0.f,0.f,0.f,0.f}, o01 = {0.f,0.f,0.f,0.f};
    f32x4 o10 = {0.f,0.f,0.f,0.f}, o11 = {0.f,0.f,0.f,0.f};
    float l0[4] = {0.f,0.f,0.f,0.f}, l1[4] = {0.f,0.f,0.f,0.f};

    __shared__ short P0[2][16 * 40];
    __shared__ short P1[2][16 * 40];

    bf16x8 kf0 = *(const bf16x8*)(Kh + (long)(ks0 + m15) * 32 + quad * 8);
    bf16x8 kf1 = *(const bf16x8*)(Kh + (long)(ks0 + 16 + m15) * 32 + quad * 8);
    bf16x8 vf0 = *(const bf16x8*)(Vh + (long)m15 * 4096 + ks0 + quad * 8);
    bf16x8 vf1 = *(const bf16x8*)(Vh + (long)(16 + m15) * 4096 + ks0 + quad * 8);

    for (int k0 = ks0; k0 < kend; k0 += 32) {
        const int buf = (k0 >> 5) & 1;
        const f32x4 zz = {0.f,0.f,0.f,0.f};
        f32x4 s00 = __builtin_amdgcn_mfma_f32_16x16x32_bf16(qf0, kf0, zz, 0, 0, 0);
        f32x4 s01 = __builtin_amdgcn_mfma_f32_16x16x32_bf16(qf0, kf1, zz, 0, 0, 0);
        f32x4 s10 = __builtin_amdgcn_mfma_f32_16x16x32_bf16(qf1, kf0, zz, 0, 0, 0);
        f32x4 s11 = __builtin_amdgcn_mfma_f32_16x16x32_bf16(qf1, kf1, zz, 0, 0, 0);
        int kn = k0 + 32;
        if (kn == kend) kn = ks0;   // keep the dead prefetch in-bounds
        kf0 = *(const bf16x8*)(Kh + (long)(kn + m15) * 32 + quad * 8);
        kf1 = *(const bf16x8*)(Kh + (long)(kn + 16 + m15) * 32 + quad * 8);
        bf16x8 nvf0 = *(const bf16x8*)(Vh + (long)m15 * 4096 + kn + quad * 8);
        bf16x8 nvf1 = *(const bf16x8*)(Vh + (long)(16 + m15) * 4096 + kn + quad * 8);
        int* Pa = (int*)P0[buf];
        int* Pb = (int*)P1[buf];
#pragma unroll
        for (int i = 0; i < 4; ++i) {
            int row = (quad * 4 + i) * 20;   // int stride (40 shorts)
            float p0 = __builtin_amdgcn_exp2f(fminf(s00[i], 100.f));
            float p1 = __builtin_amdgcn_exp2f(fminf(s01[i], 100.f));
            l0[i] += p0 + p1;
            Pa[row + m15] = (int)__builtin_amdgcn_perm(
                __float_as_uint(p1), __float_as_uint(p0), 0x07060302u);
            float p2 = __builtin_amdgcn_exp2f(fminf(s10[i], 100.f));
            float p3 = __builtin_amdgcn_exp2f(fminf(s11[i], 100.f));
            l1[i] += p2 + p3;
            Pb[row + m15] = (int)__builtin_amdgcn_perm(
                __float_as_uint(p3), __float_as_uint(p2), 0x07060302u);
        }
        __builtin_amdgcn_fence(__ATOMIC_ACQ_REL, "wavefront");  // order LDS write -> read
        bf16x8 pf0 = *(const bf16x8*)((short*)P0[buf] + m15 * 40 + quad * 8);
        bf16x8 pf1 = *(const bf16x8*)((short*)P1[buf] + m15 * 40 + quad * 8);
        o00 = __builtin_amdgcn_mfma_f32_16x16x32_bf16(pf0, vf0, o00, 0, 0, 0);
        o01 = __builtin_amdgcn_mfma_f32_16x16x32_bf16(pf0, vf1, o01, 0, 0, 0);
        o10 = __builtin_amdgcn_mfma_f32_16x16x32_bf16(pf1, vf0, o10, 0, 0, 0);
        o11 = __builtin_amdgcn_mfma_f32_16x16x32_bf16(pf1, vf1, o11, 0, 0, 0);
        vf0 = nvf0; vf1 = nvf1;
    }
#pragma unroll
    for (int i = 0; i < 4; ++i) {
        float a = l0[i], b2 = l1[i];
        a += __shfl_xor(a, 1); a += __shfl_xor(a, 2); a += __shfl_xor(a, 4); a += __shfl_xor(a, 8);
        b2 += __shfl_xor(b2, 1); b2 += __shfl_xor(b2, 2); b2 += __shfl_xor(b2, 4); b2 += __shfl_xor(b2, 8);
        l0[i] = a; l1[i] = b2;
    }
    short* po = po_base + (long)z * 2097152;
    const int base = (mh >> 2) * 128 + (mh & 3) * 32;
#pragma unroll
    for (int i = 0; i < 4; ++i) {
        int qa = q0 + quad * 4 + i;
        int qb = qa + 16;
        po[(long)qa * 512 + base + m15] = f2bf(o00[i]);
        po[(long)qa * 512 + base + 16 + m15] = f2bf(o01[i]);
        po[(long)qb * 512 + base + m15] = f2bf(o10[i]);
        po[(long)qb * 512 + base + 16 + m15] = f2bf(o11[i]);
        if (m15 == 0) {
            pl[z * 65536 + mh * 4096 + qa] = l0[i];
            pl[z * 65536 + mh * 4096 + qb] = l1[i];
        }
    }
}

// ---------------- out-proj MFMA with fused K-split combine + normalize -> bf16 hcat ----------------
__global__ __launch_bounds__(64) void k_outproj(const short* __restrict__ po,
                                                const float* __restrict__ pl,
                                                const short* __restrict__ Woutb,
                                                const void* __restrict__ bout,
                                                const int* __restrict__ flag,
                                                short* __restrict__ hcatb) {
    const int lane = threadIdx.x;
    const int m15 = lane & 15, quad = lane >> 4;
    const int c0 = blockIdx.x * 16;
    const int n0 = blockIdx.y * 16;
    const int m = blockIdx.z;
    const int n = n0 + m15;           // A-operand row for this lane
    f32x4 acc = {0.f,0.f,0.f,0.f};
#pragma unroll
    for (int k0 = 0; k0 < 128; k0 += 32) {
        const int head = m * 4 + (k0 >> 5);
        float l = pl[head * 4096 + n] + pl[65536 + head * 4096 + n];
        float inv = 1.f / fmaxf(l, 1e-30f);
        long base = (long)n * 512 + m * 128 + k0 + quad * 8;
        bf16x8 a0 = *(const bf16x8*)(po + base);
        bf16x8 a1 = *(const bf16x8*)(po + 2097152 + base);
        bf16x8 av;
#pragma unroll
        for (int j = 0; j < 8; ++j)
            av[j] = f2bf((bf2f(a0[j]) + bf2f(a1[j])) * inv);
        bf16x8 bv = *(const bf16x8*)(Woutb + (long)(m * 128 + c0 + m15) * 128 + k0 + quad * 8);
        acc = __builtin_amdgcn_mfma_f32_16x16x32_bf16(av, bv, acc, 0, 0, 0);
    }
    float bias = ldf(bout, m * 128 + c0 + m15, *flag);
#pragma unroll
    for (int i = 0; i < 4; ++i)
        hcatb[(long)(n0 + quad * 4 + i) * 512 + m * 128 + c0 + m15] = f2bf(acc[i] + bias);
}

// ---------------- mean pool: grid (16 graphs, 4 col-groups) x 128 threads ----------------
__global__ __launch_bounds__(128) void k_pool2(const short* __restrict__ hcatb,
                                               const int* __restrict__ starts,
                                               float* __restrict__ g) {
    int gr = blockIdx.x, cg = blockIdx.y;
    int c = cg * 128 + threadIdx.x;
    int beg = starts[gr], end = starts[gr + 1];
    float s = 0.f;
    for (int n = beg; n < end; ++n) s += bf2f(hcatb[(long)n * 512 + c]);
    int cnt = end - beg;
    g[gr * 512 + c] = s / (float)(cnt > 0 ? cnt : 1);
}

// ---------------- MLP head + log-softmax: one block per graph ----------------
__global__ __launch_bounds__(256) void k_head(const float* __restrict__ g,
                                              const void* __restrict__ Wf1,
                                              const void* __restrict__ bf1,
                                              const void* __restrict__ Wf2,
                                              const void* __restrict__ bf2,
                                              const int* __restrict__ flag,
                                              void* __restrict__ out) {
    __shared__ float gsm[512];
    __shared__ float hsm[256];
    const int gr = blockIdx.x;
    const int t = threadIdx.x;
    const int wb = *flag;
    gsm[t] = g[gr * 512 + t];
    gsm[256 + t] = g[gr * 512 + 256 + t];
    __syncthreads();
    float acc = 0.f;
    for (int c = 0; c < 512; ++c) acc += gsm[c] * ldf(Wf1, (long)t * 512 + c, wb);
    acc += ldf(bf1, t, wb);
    hsm[t] = fmaxf(acc, 0.f);
    __syncthreads();
    if (t < 10) {
        float a = 0.f;
        for (int k = 0; k < 256; ++k) a += hsm[k] * ldf(Wf2, (long)t * 256 + k, wb);
        gsm[t] = a + ldf(bf2, t, wb);
    }
    __syncthreads();
    if (t == 0) {
        float mx = -1e30f;
        for (int c = 0; c < 10; ++c) mx = fmaxf(mx, gsm[c]);
        float ssum = 0.f;
        for (int c = 0; c < 10; ++c) ssum += __expf(gsm[c] - mx);
        float lse = mx + __logf(ssum);
        for (int c = 0; c < 10; ++c) {
            float r = gsm[c] - lse;
            if (wb) ((bf16*)out)[gr * 10 + c] = (bf16)r;
            else    ((float*)out)[gr * 10 + c] = r;
        }
    }
}

extern "C" void kernel_launch(void* const* d_in, const int* in_sizes, int n_in,
                              void* d_out, int out_size, void* d_ws, size_t ws_size,
                              hipStream_t stream) {
    const void* x     = d_in[0];
    const int*  ei    = (const int*)d_in[1];
    const int*  batch = (const int*)d_in[2];
    const void* W1    = d_in[3];
    const void* b1    = d_in[4];
    const void* W2    = d_in[5];
    const void* b2    = d_in[6];
    const void* W_in  = d_in[7];
    const void* b_in  = d_in[8];
    const void* W_out = d_in[9];
    const void* b_out = d_in[10];
    const void* Wf1   = d_in[11];
    const void* bf1   = d_in[12];
    const void* Wf2   = d_in[13];
    const void* bf2   = d_in[14];

    const int* src = ei;
    const int* dst = ei + N_EDGES;

    // ---- workspace arena ----
    float* w = (float*)d_ws;
    size_t off = 0;
    auto alloc = [&](size_t n) { float* p = w + off; off += (n + 63) & ~(size_t)63; return p; };
    int*   flag   = (int*)alloc(64);
    float* dinv   = alloc(N_NODES);
    float* g      = alloc(N_GRAPHS * 512);
    int*   degi   = (int*)alloc(N_NODES);
    int*   offs   = (int*)alloc(N_NODES + 64);
    int*   cursor = (int*)alloc(N_NODES);
    int*   sSrc   = (int*)alloc(N_EDGES);
    int*   starts = (int*)alloc(64);
    float* pl     = alloc(KSPL * 16 * N_NODES);
    float* xbf    = alloc(262144);   // 4096*128 shorts
    float* W1bf   = alloc(4096);     // 64*128 shorts
    float* W2bf   = alloc(4096);     // 128*64 shorts
    float* Winbf  = alloc(98304);    // 1536*128 shorts
    float* Woutbf = alloc(32768);    // 4*128*128 shorts
    float* h1linbf= alloc(131072);   // 4096*64 shorts
    float* h2linbf= alloc(262144);   // 4096*128 shorts
    float* h1bf   = alloc(131072);   // 4096*64 shorts
    float* h2bf   = alloc(262144);   // 4096*128 shorts
    float* pobf   = alloc((size_t)KSPL * 1048576);  // bf16 attention partials
    float* hcatbf = alloc(524288);                  // 4096*512 shorts
    float* bufQ   = alloc(3145728);                 // Qb|Kb|VTb bf16 (12 MB)

    short* xb    = (short*)xbf;
    short* W1b   = (short*)W1bf;
    short* W2b   = (short*)W2bf;
    short* Winb  = (short*)Winbf;
    short* Woutb = (short*)Woutbf;
    short* h1lin = (short*)h1linbf;
    short* h2lin = (short*)h2linbf;
    short* h1b   = (short*)h1bf;
    short* h2b   = (short*)h2bf;
    short* po    = (short*)pobf;
    short* hcatb = (short*)hcatbf;
    short* Qb    = (short*)bufQ;
    short* Kb    = Qb + 2097152;
    short* VTb   = Qb + 4194304;

    dim3 b256(256);

    k_detect<<<dim3(1), dim3(64), 0, stream>>>(x, flag);

    // convert MFMA operand tensors to bf16 (flag-aware; bit-copy if already bf16)
    ConvSegs cs;
    cs.src0 = x;     cs.dst0 = xb;    cs.e0 = 524288;           // 4096*128
    cs.src1 = W1;    cs.dst1 = W1b;   cs.e1 = cs.e0 + 8192;     // 64*128
    cs.src2 = W2;    cs.dst2 = W2b;   cs.e2 = cs.e1 + 8192;     // 128*64
    cs.src3 = W_in;  cs.dst3 = Winb;  cs.e3 = cs.e2 + 196608;   // 1536*128
    cs.src4 = W_out; cs.dst4 = Woutb; cs.e4 = cs.e3 + 65536;    // 4*128*128
    k_tobf16<<<dim3((802816 + 255) / 256), b256, 0, stream>>>(cs, flag);

    hipMemsetAsync(degi, 0, N_NODES * sizeof(int), stream);
    k_deg<<<dim3((N_EDGES + 255) / 256), b256, 0, stream>>>(dst, degi);
    k_prep<<<dim3(1), dim3(1024), 0, stream>>>(degi, batch, offs, cursor, dinv, starts);
    k_sortedges<<<dim3((N_EDGES + 255) / 256), b256, 0, stream>>>(src, dst, cursor, sSrc);

    // GCN1: h1lin(bf16) = xb @ W1b^T (MFMA); gather -> h1b
    k_mfma_gemm_s<<<dim3(4, N_NODES / 16), dim3(64), 0, stream>>>(
        xb, F_IN, W1b, h1lin, 64, F_IN);
    k_gather64<<<dim3(N_NODES), dim3(64), 0, stream>>>(h1lin, offs, sSrc, dinv, b1, flag, h1b);

    // GCN2: h2lin(bf16) = h1b @ W2b^T (MFMA); gather -> h2b
    k_mfma_gemm_s<<<dim3(8, N_NODES / 16), dim3(64), 0, stream>>>(
        h1b, 64, W2b, h2lin, 128, 64);
    k_gather128<<<dim3(N_NODES), dim3(128), 0, stream>>>(h2lin, offs, sSrc, dinv, b2, flag, h2b);

    // fused qkv (MFMA + scatter epilogue) -> Qb/Kb/VTb
    k_qkv<<<dim3(96, N_NODES / 16), dim3(64), 0, stream>>>(
        h2b, Winb, b_in, flag, Qb, Kb, VTb);

    // MFMA flash attention v7 (XCD head-pinned, exp2, packed P, bf16 partials)
    k_attn_v7<<<dim3(4096), dim3(64), 0, stream>>>(Qb, Kb, VTb, po, pl, N_NODES / KSPL);

    // out-proj with fused combine+normalize -> bf16 hcat
    k_outproj<<<dim3(8, N_NODES / 16, 4), dim3(64), 0, stream>>>(
        po, pl, Woutb, b_out, flag, hcatb);

    // mean pool (parallel) + MLP head + log-softmax
    k_pool2<<<dim3(N_GRAPHS, 4), dim3(128), 0, stream>>>(hcatb, starts, g);
    k_head<<<dim3(N_GRAPHS), b256, 0, stream>>>(g, Wf1, bf1, Wf2, bf2, flag, d_out);
}

// Round 21
// 386.840 us; speedup vs baseline: 1.1048x; 1.1048x over previous
//
#include <hip/hip_runtime.h>
#include <hip/hip_bf16.h>

#define N_NODES 4096
#define N_EDGES 131072
#define N_GRAPHS 16
#define F_IN 128
#define D 128
#define QKVLD 1536   // 4 modules * 384
#define KSPL 2

typedef __hip_bfloat16 bf16;
typedef __attribute__((ext_vector_type(4))) float f32x4;
typedef __attribute__((ext_vector_type(8))) short bf16x8;

// float -> bf16 bits (RNE)
__device__ __forceinline__ short f2bf(float f) {
    unsigned u = __float_as_uint(f);
    unsigned r = (u + 0x7fffu + ((u >> 16) & 1u)) >> 16;
    return (short)r;
}
__device__ __forceinline__ float bf2f(short b) {
    return __uint_as_float(((unsigned)(unsigned short)b) << 16);
}
// Flagged load: isbf!=0 -> buffer holds bf16, else fp32. i is an ELEMENT index.
__device__ __forceinline__ float ldf(const void* p, long i, int isbf) {
    return isbf ? bf2f(((const short*)p)[i]) : ((const float*)p)[i];
}

// ---------------- dtype detector (bf16 data: all halfword exponents < 134) ----------------
__global__ void k_detect(const void* __restrict__ x, int* __restrict__ flag) {
    if (threadIdx.x == 0 && blockIdx.x == 0) {
        const unsigned short* h = (const unsigned short*)x;
        int bf = 1;
        for (int i = 0; i < 64; ++i) {
            int e = (h[i] >> 7) & 0xFF;
            if (e >= 134) { bf = 0; break; }
        }
        *flag = bf;
    }
}

// ---------------- flag-aware conversion of MFMA operand tensors to bf16 ----------------
struct ConvSegs {
    const void* src0; const void* src1; const void* src2; const void* src3; const void* src4;
    short* dst0; short* dst1; short* dst2; short* dst3; short* dst4;
    int e0, e1, e2, e3, e4;
};
__global__ void k_tobf16(ConvSegs s, const int* __restrict__ flag) {
    int idx = blockIdx.x * 256 + threadIdx.x;
    int isbf = *flag;
    const void* src; short* dst; int base;
    if (idx < s.e0)      { src = s.src0; dst = s.dst0; base = 0; }
    else if (idx < s.e1) { src = s.src1; dst = s.dst1; base = s.e0; }
    else if (idx < s.e2) { src = s.src2; dst = s.dst2; base = s.e1; }
    else if (idx < s.e3) { src = s.src3; dst = s.dst3; base = s.e2; }
    else if (idx < s.e4) { src = s.src4; dst = s.dst4; base = s.e3; }
    else return;
    int i = idx - base;
    dst[i] = f2bf(ldf(src, i, isbf));
}

__global__ void k_deg(const int* __restrict__ dst, int* __restrict__ degi) {
    int e = blockIdx.x * 256 + threadIdx.x;
    if (e < N_EDGES) atomicAdd(&degi[dst[e]], 1);
}

// ---------------- fused prep: degree scan + dinv + batch boundaries (one block) ----------------
__global__ __launch_bounds__(1024) void k_prep(const int* __restrict__ degi,
                                               const int* __restrict__ batch,
                                               int* __restrict__ offs,
                                               int* __restrict__ cursor,
                                               float* __restrict__ dinv,
                                               int* __restrict__ starts) {
    __shared__ int part[1024];
    int t = threadIdx.x;
    int4 v = *(const int4*)(degi + t * 4);
    int dv[4] = {v.x, v.y, v.z, v.w};
    int s = dv[0] + dv[1] + dv[2] + dv[3];
    part[t] = s;
    __syncthreads();
    for (int ofs = 1; ofs < 1024; ofs <<= 1) {
        int val = (t >= ofs) ? part[t - ofs] : 0;
        __syncthreads();
        part[t] += val;
        __syncthreads();
    }
    int o = part[t] - s;
#pragma unroll
    for (int j = 0; j < 4; ++j) {
        int n = t * 4 + j;
        offs[n] = o; cursor[n] = o;
        o += dv[j];
        dinv[n] = rsqrtf((float)(dv[j] + 1));   // +1 self loop
    }
    if (t == 1023) offs[4096] = o;
    // batch boundaries (batch is sorted)
#pragma unroll
    for (int j = 0; j < 4; ++j) {
        int n = t * 4 + j;
        int b = batch[n];
        if (n == 0) { for (int g2 = 0; g2 <= b; ++g2) starts[g2] = 0; }
        else {
            int pb = batch[n - 1];
            for (int g2 = pb + 1; g2 <= b; ++g2) starts[g2] = n;
        }
        if (n == N_NODES - 1) { for (int g2 = b + 1; g2 <= N_GRAPHS; ++g2) starts[g2] = N_NODES; }
    }
}

__global__ void k_sortedges(const int* __restrict__ src, const int* __restrict__ dst,
                            int* __restrict__ cursor, int* __restrict__ sSrc) {
    int e = blockIdx.x * 256 + threadIdx.x;
    if (e >= N_EDGES) return;
    int d = dst[e];
    int pos = atomicAdd(&cursor[d], 1);
    sSrc[pos] = src[e];
}

// ---------------- MFMA GEMM, bf16 out (no bias): C[M][ldc] bf16 = A @ W^T ----------------
__global__ __launch_bounds__(64) void k_mfma_gemm_s(const short* __restrict__ A, int lda,
                                                    const short* __restrict__ W,
                                                    short* __restrict__ C, int ldc, int K) {
    const int lane = threadIdx.x;
    const int m15 = lane & 15, quad = lane >> 4;
    const int c0 = blockIdx.x * 16;
    const int n0 = blockIdx.y * 16;
    f32x4 acc = {0.f, 0.f, 0.f, 0.f};
    for (int k0 = 0; k0 < K; k0 += 32) {
        bf16x8 a = *(const bf16x8*)(A + (long)(n0 + m15) * lda + k0 + quad * 8);
        bf16x8 b = *(const bf16x8*)(W + (long)(c0 + m15) * K + k0 + quad * 8);
        acc = __builtin_amdgcn_mfma_f32_16x16x32_bf16(a, b, acc, 0, 0, 0);
    }
#pragma unroll
    for (int i = 0; i < 4; ++i)
        C[(long)(n0 + quad * 4 + i) * ldc + c0 + m15] = f2bf(acc[i]);
}

// ---------------- fused qkv MFMA with scatter epilogue -> Qb/Kb/VTb bf16 ----------------
// Q pre-scaled by log2(e)/sqrt(32). V stored with per-32-tile slot permutation
// phys = 2*(off&15) + (off>=16) matching packed-P column order.
__global__ __launch_bounds__(64) void k_qkv(const short* __restrict__ h2b,
                                            const short* __restrict__ Winb,
                                            const void* __restrict__ bin,
                                            const int* __restrict__ flag,
                                            short* __restrict__ Qb,
                                            short* __restrict__ Kb,
                                            short* __restrict__ VTb) {
    const int lane = threadIdx.x;
    const int m15 = lane & 15, quad = lane >> 4;
    const int c0 = blockIdx.x * 16;
    const int n0 = blockIdx.y * 16;
    f32x4 acc = {0.f, 0.f, 0.f, 0.f};
#pragma unroll
    for (int k0 = 0; k0 < 128; k0 += 32) {
        bf16x8 a = *(const bf16x8*)(h2b + (long)(n0 + m15) * 128 + k0 + quad * 8);
        bf16x8 b = *(const bf16x8*)(Winb + (long)(c0 + m15) * 128 + k0 + quad * 8);
        acc = __builtin_amdgcn_mfma_f32_16x16x32_bf16(a, b, acc, 0, 0, 0);
    }
    const int c = c0 + m15;           // D layout: col = lane&15
    const int mmod = c / 384;
    const int r = c - mmod * 384;
    const int sect = r >> 7;          // 0=q, 1=k, 2=v (uniform per block)
    const int rr = r & 127;
    const int head = mmod * 4 + (rr >> 5);
    const int d = rr & 31;
    const float bias = ldf(bin, c, *flag);
    if (sect == 0) {
        const float scale = 0.17677669529663687f * 1.4426950408889634f;  // 1/sqrt(32)*log2(e)
#pragma unroll
        for (int i = 0; i < 4; ++i)   // D layout: row = quad*4 + i
            Qb[(long)head * 131072 + (long)(n0 + quad * 4 + i) * 32 + d] = f2bf((acc[i] + bias) * scale);
    } else if (sect == 1) {
#pragma unroll
        for (int i = 0; i < 4; ++i)
            Kb[(long)head * 131072 + (long)(n0 + quad * 4 + i) * 32 + d] = f2bf(acc[i] + bias);
    } else {
        long vbase = (long)head * 131072 + (long)d * 4096;
#pragma unroll
        for (int i = 0; i < 4; ++i) {
            int n = n0 + quad * 4 + i;
            int phys = (n & ~31) | (((n & 15) << 1) | ((n >> 4) & 1));
            VTb[vbase + phys] = f2bf(acc[i] + bias);
        }
    }
}

// ---------------- GCN gather (CSR, no atomics, bf16 lin input): one block per node ----------------
__global__ __launch_bounds__(64) void k_gather64(const short* __restrict__ hlin,
                                                 const int* __restrict__ offs,
                                                 const int* __restrict__ sSrc,
                                                 const float* __restrict__ dinv,
                                                 const void* __restrict__ bias,
                                                 const int* __restrict__ flag,
                                                 short* __restrict__ houtb) {
    int n = blockIdx.x;
    int c = threadIdx.x;
    int beg = offs[n], end = offs[n + 1];
    float di = dinv[n];
    float acc = 0.f;
    for (int j = beg; j < end; ++j) {
        int s = sSrc[j];
        acc += dinv[s] * bf2f(hlin[(long)s * 64 + c]);
    }
    float v = fmaxf(di * acc + di * di * bf2f(hlin[(long)n * 64 + c]) + ldf(bias, c, *flag), 0.f);
    houtb[(long)n * 64 + c] = f2bf(v);
}

__global__ __launch_bounds__(128) void k_gather128(const short* __restrict__ hlin,
                                                   const int* __restrict__ offs,
                                                   const int* __restrict__ sSrc,
                                                   const float* __restrict__ dinv,
                                                   const void* __restrict__ bias,
                                                   const int* __restrict__ flag,
                                                   short* __restrict__ h2b) {
    int n = blockIdx.x;
    int c = threadIdx.x;
    int beg = offs[n], end = offs[n + 1];
    float di = dinv[n];
    float acc = 0.f;
    for (int j = beg; j < end; ++j) {
        int s = sSrc[j];
        acc += dinv[s] * bf2f(hlin[(long)s * 128 + c]);
    }
    float v = fmaxf(di * acc + di * di * bf2f(hlin[(long)n * 128 + c]) + ldf(bias, c, *flag), 0.f);
    h2b[(long)n * 128 + c] = f2bf(v);
}

// ---------------- MFMA flash attention v7: XCD head-pinned, exp2, packed P, bf16 partials ----------------
__global__ __launch_bounds__(64) void k_attn_v7(const short* __restrict__ Qb,
                                                const short* __restrict__ Kb,
                                                const short* __restrict__ VTb,
                                                short* __restrict__ po_base,
                                                float* __restrict__ pl,
                                                int ksize) {
    const int lane = threadIdx.x;
    const int m15 = lane & 15, quad = lane >> 4;
    const int b = blockIdx.x;
    const int mh = (b & 7) + 8 * (b >> 11);     // head, pinned to b%8 (XCD round-robin)
    const int rem = (b >> 3) & 255;
    const int z = rem >> 7;                     // K-split
    const int q0 = (rem & 127) * 32;            // q tile
    const long hoff = (long)mh * 131072;
    const short* Qh = Qb + hoff;
    const short* Kh = Kb + hoff;
    const short* Vh = VTb + hoff;     // [32][4096], slot-permuted
    const int ks0 = z * ksize;
    const int kend = ks0 + ksize;

    const bf16x8 qf0 = *(const bf16x8*)(Qh + (long)(q0 + m15) * 32 + quad * 8);
    const bf16x8 qf1 = *(const bf16x8*)(Qh + (long)(q0 + 16 + m15) * 32 + quad * 8);

    f32x4 o00 = {0.f,0.f,0.f,0.f}, o01 = {0.f,0.f,0.f,0.f};
    f32x4 o10 = {0.f,0.f,0.f,0.f}, o11 = {0.f,0.f,0.f,0.f};
    float l0[4] = {0.f,0.f,0.f,0.f}, l1[4] = {0.f,0.f,0.f,0.f};

    __shared__ short P0[2][16 * 40];
    __shared__ short P1[2][16 * 40];

    bf16x8 kf0 = *(const bf16x8*)(Kh + (long)(ks0 + m15) * 32 + quad * 8);
    bf16x8 kf1 = *(const bf16x8*)(Kh + (long)(ks0 + 16 + m15) * 32 + quad * 8);
    bf16x8 vf0 = *(const bf16x8*)(Vh + (long)m15 * 4096 + ks0 + quad * 8);
    bf16x8 vf1 = *(const bf16x8*)(Vh + (long)(16 + m15) * 4096 + ks0 + quad * 8);

    for (int k0 = ks0; k0 < kend; k0 += 32) {
        const int buf = (k0 >> 5) & 1;
        const f32x4 zz = {0.f,0.f,0.f,0.f};
        f32x4 s00 = __builtin_amdgcn_mfma_f32_16x16x32_bf16(qf0, kf0, zz, 0, 0, 0);
        f32x4 s01 = __builtin_amdgcn_mfma_f32_16x16x32_bf16(qf0, kf1, zz, 0, 0, 0);
        f32x4 s10 = __builtin_amdgcn_mfma_f32_16x16x32_bf16(qf1, kf0, zz, 0, 0, 0);
        f32x4 s11 = __builtin_amdgcn_mfma_f32_16x16x32_bf16(qf1, kf1, zz, 0, 0, 0);
        int kn = k0 + 32;
        if (kn == kend) kn = ks0;   // keep the dead prefetch in-bounds
        kf0 = *(const bf16x8*)(Kh + (long)(kn + m15) * 32 + quad * 8);
        kf1 = *(const bf16x8*)(Kh + (long)(kn + 16 + m15) * 32 + quad * 8);
        bf16x8 nvf0 = *(const bf16x8*)(Vh + (long)m15 * 4096 + kn + quad * 8);
        bf16x8 nvf1 = *(const bf16x8*)(Vh + (long)(16 + m15) * 4096 + kn + quad * 8);
        int* Pa = (int*)P0[buf];
        int* Pb = (int*)P1[buf];
#pragma unroll
        for (int i = 0; i < 4; ++i) {
            int row = (quad * 4 + i) * 20;   // int stride (40 shorts)
            float p0 = __builtin_amdgcn_exp2f(fminf(s00[i], 100.f));
            float p1 = __builtin_amdgcn_exp2f(fminf(s01[i], 100.f));
            l0[i] += p0 + p1;
            Pa[row + m15] = (int)__builtin_amdgcn_perm(
                __float_as_uint(p1), __float_as_uint(p0), 0x07060302u);
            float p2 = __builtin_amdgcn_exp2f(fminf(s10[i], 100.f));
            float p3 = __builtin_amdgcn_exp2f(fminf(s11[i], 100.f));
            l1[i] += p2 + p3;
            Pb[row + m15] = (int)__builtin_amdgcn_perm(
                __float_as_uint(p3), __float_as_uint(p2), 0x07060302u);
        }
        __builtin_amdgcn_fence(__ATOMIC_ACQ_REL, "wavefront");  // order LDS write -> read
        bf16x8 pf0 = *(const bf16x8*)((short*)P0[buf] + m15 * 40 + quad * 8);
        bf16x8 pf1 = *(const bf16x8*)((short*)P1[buf] + m15 * 40 + quad * 8);
        o00 = __builtin_amdgcn_mfma_f32_16x16x32_bf16(pf0, vf0, o00, 0, 0, 0);
        o01 = __builtin_amdgcn_mfma_f32_16x16x32_bf16(pf0, vf1, o01, 0, 0, 0);
        o10 = __builtin_amdgcn_mfma_f32_16x16x32_bf16(pf1, vf0, o10, 0, 0, 0);
        o11 = __builtin_amdgcn_mfma_f32_16x16x32_bf16(pf1, vf1, o11, 0, 0, 0);
        vf0 = nvf0; vf1 = nvf1;
    }
#pragma unroll
    for (int i = 0; i < 4; ++i) {
        float a = l0[i], b2 = l1[i];
        a += __shfl_xor(a, 1); a += __shfl_xor(a, 2); a += __shfl_xor(a, 4); a += __shfl_xor(a, 8);
        b2 += __shfl_xor(b2, 1); b2 += __shfl_xor(b2, 2); b2 += __shfl_xor(b2, 4); b2 += __shfl_xor(b2, 8);
        l0[i] = a; l1[i] = b2;
    }
    short* po = po_base + (long)z * 2097152;
    const int base = (mh >> 2) * 128 + (mh & 3) * 32;
#pragma unroll
    for (int i = 0; i < 4; ++i) {
        int qa = q0 + quad * 4 + i;
        int qb = qa + 16;
        po[(long)qa * 512 + base + m15] = f2bf(o00[i]);
        po[(long)qa * 512 + base + 16 + m15] = f2bf(o01[i]);
        po[(long)qb * 512 + base + m15] = f2bf(o10[i]);
        po[(long)qb * 512 + base + 16 + m15] = f2bf(o11[i]);
        if (m15 == 0) {
            pl[z * 65536 + mh * 4096 + qa] = l0[i];
            pl[z * 65536 + mh * 4096 + qb] = l1[i];
        }
    }
}

// ---------------- out-proj MFMA with fused K-split combine + normalize -> fp32 hcat ----------------
// grid (8, 256, 4). A-fragment built in-register from bf16 partials (po0+po1)/l.
__global__ __launch_bounds__(64) void k_outproj(const short* __restrict__ po,
                                                const float* __restrict__ pl,
                                                const short* __restrict__ Woutb,
                                                const void* __restrict__ bout,
                                                const int* __restrict__ flag,
                                                float* __restrict__ hcat) {
    const int lane = threadIdx.x;
    const int m15 = lane & 15, quad = lane >> 4;
    const int c0 = blockIdx.x * 16;
    const int n0 = blockIdx.y * 16;
    const int m = blockIdx.z;
    const int n = n0 + m15;           // A-operand row for this lane
    f32x4 acc = {0.f,0.f,0.f,0.f};
#pragma unroll
    for (int k0 = 0; k0 < 128; k0 += 32) {
        const int head = m * 4 + (k0 >> 5);
        float l = pl[head * 4096 + n] + pl[65536 + head * 4096 + n];
        float inv = 1.f / fmaxf(l, 1e-30f);
        long base = (long)n * 512 + m * 128 + k0 + quad * 8;
        bf16x8 a0 = *(const bf16x8*)(po + base);
        bf16x8 a1 = *(const bf16x8*)(po + 2097152 + base);
        bf16x8 av;
#pragma unroll
        for (int j = 0; j < 8; ++j)
            av[j] = f2bf((bf2f(a0[j]) + bf2f(a1[j])) * inv);
        bf16x8 bv = *(const bf16x8*)(Woutb + (long)(m * 128 + c0 + m15) * 128 + k0 + quad * 8);
        acc = __builtin_amdgcn_mfma_f32_16x16x32_bf16(av, bv, acc, 0, 0, 0);
    }
    float bias = ldf(bout, m * 128 + c0 + m15, *flag);
#pragma unroll
    for (int i = 0; i < 4; ++i)
        hcat[(long)(n0 + quad * 4 + i) * 512 + m * 128 + c0 + m15] = acc[i] + bias;
}

// ---------------- mean pool via sorted-batch boundaries (no atomics) ----------------
__global__ __launch_bounds__(128) void k_pool2(const float* __restrict__ hcat,
                                               const int* __restrict__ starts,
                                               float* __restrict__ g) {
    int gr = blockIdx.x, cg = blockIdx.y;
    int c = cg * 128 + threadIdx.x;
    int beg = starts[gr], end = starts[gr + 1];
    float s = 0.f;
    for (int n = beg; n < end; ++n) s += hcat[(long)n * 512 + c];
    int cnt = end - beg;
    g[gr * 512 + c] = s / (float)(cnt > 0 ? cnt : 1);
}

// ---------------- MLP head: fp32 A, flag-aware W/bias (original tensors) ----------------
__global__ void k_gemm_mlp(const float* __restrict__ A, int lda,
                           const void* __restrict__ W,
                           const void* __restrict__ bias,
                           const int* __restrict__ flag,
                           float* __restrict__ C, int ldc,
                           int M, int N, int K, int relu) {
    const int wb = *flag;
    __shared__ float As[16][17];
    __shared__ float Ws[16][17];
    int tx = threadIdx.x, ty = threadIdx.y;
    int row = blockIdx.y * 16 + ty;
    int col = blockIdx.x * 16 + tx;
    float acc = 0.f;
    for (int k0 = 0; k0 < K; k0 += 16) {
        As[ty][tx] = (row < M && (k0 + tx) < K) ? A[(long)row * lda + k0 + tx] : 0.f;
        int wrow = blockIdx.x * 16 + ty;
        Ws[ty][tx] = (wrow < N && (k0 + tx) < K) ? ldf(W, (long)wrow * K + k0 + tx, wb) : 0.f;
        __syncthreads();
#pragma unroll
        for (int kk = 0; kk < 16; ++kk) acc += As[ty][kk] * Ws[tx][kk];
        __syncthreads();
    }
    if (row < M && col < N) {
        if (bias) acc += ldf(bias, col, wb);
        if (relu) acc = fmaxf(acc, 0.f);
        C[(long)row * ldc + col] = acc;
    }
}

// ---------------- log softmax over 10 classes, dtype-flagged output ----------------
__global__ void k_logsoftmax(const float* __restrict__ logits, const int* __restrict__ flag,
                             void* __restrict__ out) {
    int t = threadIdx.x;
    if (t >= N_GRAPHS) return;
    int isbf = *flag;
    float v[10];
    float mx = -1e30f;
    for (int c = 0; c < 10; ++c) { v[c] = logits[t * 10 + c]; mx = fmaxf(mx, v[c]); }
    float s = 0.f;
    for (int c = 0; c < 10; ++c) s += __expf(v[c] - mx);
    float lse = mx + __logf(s);
    for (int c = 0; c < 10; ++c) {
        float r = v[c] - lse;
        if (isbf) ((bf16*)out)[t * 10 + c] = (bf16)r;
        else      ((float*)out)[t * 10 + c] = r;
    }
}

extern "C" void kernel_launch(void* const* d_in, const int* in_sizes, int n_in,
                              void* d_out, int out_size, void* d_ws, size_t ws_size,
                              hipStream_t stream) {
    const void* x     = d_in[0];
    const int*  ei    = (const int*)d_in[1];
    const int*  batch = (const int*)d_in[2];
    const void* W1    = d_in[3];
    const void* b1    = d_in[4];
    const void* W2    = d_in[5];
    const void* b2    = d_in[6];
    const void* W_in  = d_in[7];
    const void* b_in  = d_in[8];
    const void* W_out = d_in[9];
    const void* b_out = d_in[10];
    const void* Wf1   = d_in[11];
    const void* bf1   = d_in[12];
    const void* Wf2   = d_in[13];
    const void* bf2   = d_in[14];

    const int* src = ei;
    const int* dst = ei + N_EDGES;

    // ---- workspace arena ----
    float* w = (float*)d_ws;
    size_t off = 0;
    auto alloc = [&](size_t n) { float* p = w + off; off += (n + 63) & ~(size_t)63; return p; };
    int*   flag   = (int*)alloc(64);
    float* dinv   = alloc(N_NODES);
    float* g      = alloc(N_GRAPHS * 512);
    float* hid    = alloc(N_GRAPHS * 256);
    float* logits = alloc(N_GRAPHS * 10);
    int*   degi   = (int*)alloc(N_NODES);
    int*   offs   = (int*)alloc(N_NODES + 64);
    int*   cursor = (int*)alloc(N_NODES);
    int*   sSrc   = (int*)alloc(N_EDGES);
    int*   starts = (int*)alloc(64);
    float* pl     = alloc(KSPL * 16 * N_NODES);
    float* xbf    = alloc(262144);   // 4096*128 shorts
    float* W1bf   = alloc(4096);     // 64*128 shorts
    float* W2bf   = alloc(4096);     // 128*64 shorts
    float* Winbf  = alloc(98304);    // 1536*128 shorts
    float* Woutbf = alloc(32768);    // 4*128*128 shorts
    float* h1linbf= alloc(131072);   // 4096*64 shorts
    float* h2linbf= alloc(262144);   // 4096*128 shorts
    float* h1bf   = alloc(131072);   // 4096*64 shorts
    float* h2bf   = alloc(262144);   // 4096*128 shorts
    float* pobf   = alloc((size_t)KSPL * 1048576);  // bf16 attention partials
    float* hcat   = alloc(2097152);                 // 4096*512 fp32
    float* bufQ   = alloc(3145728);                 // Qb|Kb|VTb bf16 (12 MB)

    short* xb    = (short*)xbf;
    short* W1b   = (short*)W1bf;
    short* W2b   = (short*)W2bf;
    short* Winb  = (short*)Winbf;
    short* Woutb = (short*)Woutbf;
    short* h1lin = (short*)h1linbf;
    short* h2lin = (short*)h2linbf;
    short* h1b   = (short*)h1bf;
    short* h2b   = (short*)h2bf;
    short* po    = (short*)pobf;
    short* Qb    = (short*)bufQ;
    short* Kb    = Qb + 2097152;
    short* VTb   = Qb + 4194304;

    dim3 b256(256);

    k_detect<<<dim3(1), dim3(64), 0, stream>>>(x, flag);

    // convert MFMA operand tensors to bf16 (flag-aware; bit-copy if already bf16)
    ConvSegs cs;
    cs.src0 = x;     cs.dst0 = xb;    cs.e0 = 524288;           // 4096*128
    cs.src1 = W1;    cs.dst1 = W1b;   cs.e1 = cs.e0 + 8192;     // 64*128
    cs.src2 = W2;    cs.dst2 = W2b;   cs.e2 = cs.e1 + 8192;     // 128*64
    cs.src3 = W_in;  cs.dst3 = Winb;  cs.e3 = cs.e2 + 196608;   // 1536*128
    cs.src4 = W_out; cs.dst4 = Woutb; cs.e4 = cs.e3 + 65536;    // 4*128*128
    k_tobf16<<<dim3((802816 + 255) / 256), b256, 0, stream>>>(cs, flag);

    hipMemsetAsync(degi, 0, N_NODES * sizeof(int), stream);
    k_deg<<<dim3((N_EDGES + 255) / 256), b256, 0, stream>>>(dst, degi);
    k_prep<<<dim3(1), dim3(1024), 0, stream>>>(degi, batch, offs, cursor, dinv, starts);
    k_sortedges<<<dim3((N_EDGES + 255) / 256), b256, 0, stream>>>(src, dst, cursor, sSrc);

    // GCN1: h1lin(bf16) = xb @ W1b^T (MFMA); gather -> h1b
    k_mfma_gemm_s<<<dim3(4, N_NODES / 16), dim3(64), 0, stream>>>(
        xb, F_IN, W1b, h1lin, 64, F_IN);
    k_gather64<<<dim3(N_NODES), dim3(64), 0, stream>>>(h1lin, offs, sSrc, dinv, b1, flag, h1b);

    // GCN2: h2lin(bf16) = h1b @ W2b^T (MFMA); gather -> h2b
    k_mfma_gemm_s<<<dim3(8, N_NODES / 16), dim3(64), 0, stream>>>(
        h1b, 64, W2b, h2lin, 128, 64);
    k_gather128<<<dim3(N_NODES), dim3(128), 0, stream>>>(h2lin, offs, sSrc, dinv, b2, flag, h2b);

    // fused qkv (MFMA + scatter epilogue) -> Qb/Kb/VTb
    k_qkv<<<dim3(96, N_NODES / 16), dim3(64), 0, stream>>>(
        h2b, Winb, b_in, flag, Qb, Kb, VTb);

    // MFMA flash attention v7 (XCD head-pinned, exp2, packed P, bf16 partials)
    k_attn_v7<<<dim3(4096), dim3(64), 0, stream>>>(Qb, Kb, VTb, po, pl, N_NODES / KSPL);

    // out-proj with fused combine+normalize -> fp32 hcat
    k_outproj<<<dim3(8, N_NODES / 16, 4), dim3(64), 0, stream>>>(
        po, pl, Woutb, b_out, flag, hcat);

    // mean pool + MLP head + log-softmax (r18-proven epilogue shape)
    k_pool2<<<dim3(N_GRAPHS, 4), dim3(128), 0, stream>>>(hcat, starts, g);
    k_gemm_mlp<<<dim3(256 / 16, 1), dim3(16, 16), 0, stream>>>(
        g, 512, Wf1, bf1, flag, hid, 256, N_GRAPHS, 256, 512, 1);
    k_gemm_mlp<<<dim3(1, 1), dim3(16, 16), 0, stream>>>(
        hid, 256, Wf2, bf2, flag, logits, 10, N_GRAPHS, 10, 256, 0);
    k_logsoftmax<<<dim3(1), dim3(64), 0, stream>>>(logits, flag, d_out);
}